// Round 2
// baseline (23625.558 us; speedup 1.0000x reference)
//
#include <hip/hip_runtime.h>
#include <hip/hip_bf16.h>
#include <stdint.h>
#include <math.h>

// Problem constants (fixed by the reference)
#define SEQ    2048
#define EMB    1024
#define HID    1024
#define G4     4096      // 4*HID
#define NEMO   16
#define NLAB   7

// LSTM persistent-kernel partition: 128 blocks x 256 threads (4 waves).
// Block b owns units [8b, 8b+8). Row mapping r = gate*8 + unit, wave = r&3:
// all 4 gates of unit u land in wave (u&3)  ->  each wave owns units {wv, wv+4}
// completely and the whole step runs with NO barriers and NO LDS.
#define NB 128

// Fast branch-free sigmoid/tanh (v_exp_f32 + v_rcp_f32).
__device__ __forceinline__ float fsig(float x) {
    return __builtin_amdgcn_rcpf(1.0f + __builtin_amdgcn_exp2f(x * -1.4426950408889634f));
}
__device__ __forceinline__ float ftanh(float x) {
    // tanh(x) = 2*sigmoid(2x) - 1 ; exp2 under/overflow saturates correctly.
    return 2.0f * __builtin_amdgcn_rcpf(1.0f + __builtin_amdgcn_exp2f(x * -2.8853900817779268f)) - 1.0f;
}

// ---------------- k_init: emoji average + htag reset ----------------
__global__ void k_init(const int* __restrict__ emoji_ids,
                       const float* __restrict__ emoji_emb,
                       float* __restrict__ eave,
                       unsigned long long* __restrict__ htag)
{
    int t = threadIdx.x;
    int ids[NEMO];
#pragma unroll
    for (int n = 0; n < NEMO; ++n) ids[n] = emoji_ids[n];
    for (int e = t; e < EMB; e += 256) {
        float s = 0.f;
#pragma unroll
        for (int n = 0; n < NEMO; ++n) s += emoji_emb[(size_t)ids[n] * EMB + e];
        eave[e] = s * (1.0f / 16.0f);
    }
    // htag[2][HID]: tag=0, value=0.0f  (h_{-1} = zeros, parity-1 buffer)
    for (int i = t; i < 2 * HID; i += 256) htag[i] = 0ull;
}

// ---------------- k_cvec: cvec = comb_W[:,1024:] @ eave + comb_b ----------------
__global__ void k_cvec(const float* __restrict__ combW,
                       const float* __restrict__ combB,
                       const float* __restrict__ eave,
                       float* __restrict__ cvec)
{
    // 64 blocks x 256 threads = 256 waves; 4 rows per wave
    int gw   = (blockIdx.x * 256 + threadIdx.x) >> 6;
    int lane = threadIdx.x & 63;
#pragma unroll
    for (int rr = 0; rr < 4; ++rr) {
        int r = gw * 4 + rr;
        const float* wrow = combW + (size_t)r * 2048 + 1024;
        float s = 0.f;
        for (int k = lane; k < EMB; k += 64) s = fmaf(wrow[k], eave[k], s);
#pragma unroll
        for (int off = 1; off < 64; off <<= 1) s += __shfl_xor(s, off);
        if (lane == 0) cvec[r] = s + combB[r];
    }
}

// ---------------- k_gemm: O[m][n] = sum_k Arow(m)[k]*B[n*bstride+k] + bias (+relu) ----
// BM=BN=128, BK=16, 256 threads, 8x8 microtile. K fixed at 1024, dims divide evenly.
__global__ __launch_bounds__(256) void k_gemm(
    const float* __restrict__ Asrc,
    const int*   __restrict__ ids,       // if non-null: A row m = emb[ids[m]]
    const float* __restrict__ emb,
    const float* __restrict__ B, int bstride,
    const float* __restrict__ bias1,
    const float* __restrict__ bias2,     // optional second bias
    float* __restrict__ O, int N, int relu)
{
    __shared__ float As[16][128];
    __shared__ float Bs[16][128];
    const int tid  = threadIdx.x;
    const int row0 = blockIdx.y * 128;
    const int col0 = blockIdx.x * 128;
    const int lr = tid >> 2;     // 0..63: staging row
    const int kq = tid & 3;      // 0..3 : k quad
    const float *ar0, *ar1;
    if (ids) {
        ar0 = emb + (size_t)ids[row0 + lr]      * 1024;
        ar1 = emb + (size_t)ids[row0 + lr + 64] * 1024;
    } else {
        ar0 = Asrc + (size_t)(row0 + lr)      * 1024;
        ar1 = Asrc + (size_t)(row0 + lr + 64) * 1024;
    }
    const float* br0 = B + (size_t)(col0 + lr)      * bstride;
    const float* br1 = B + (size_t)(col0 + lr + 64) * bstride;
    const int tx = tid & 15, ty = tid >> 4;

    float acc[8][8];
#pragma unroll
    for (int i = 0; i < 8; ++i)
#pragma unroll
        for (int j = 0; j < 8; ++j) acc[i][j] = 0.f;

    for (int k0 = 0; k0 < 1024; k0 += 16) {
        float4 a0 = *(const float4*)(ar0 + k0 + kq * 4);
        float4 a1 = *(const float4*)(ar1 + k0 + kq * 4);
        float4 b0 = *(const float4*)(br0 + k0 + kq * 4);
        float4 b1 = *(const float4*)(br1 + k0 + kq * 4);
        __syncthreads();
        {
            const float* pa0 = &a0.x; const float* pa1 = &a1.x;
            const float* pb0 = &b0.x; const float* pb1 = &b1.x;
#pragma unroll
            for (int e = 0; e < 4; ++e) {
                As[kq * 4 + e][lr]      = pa0[e];
                As[kq * 4 + e][lr + 64] = pa1[e];
                Bs[kq * 4 + e][lr]      = pb0[e];
                Bs[kq * 4 + e][lr + 64] = pb1[e];
            }
        }
        __syncthreads();
#pragma unroll
        for (int kk = 0; kk < 16; ++kk) {
            float af[8], bf[8];
            *(float4*)(af)     = *(const float4*)&As[kk][ty * 8];
            *(float4*)(af + 4) = *(const float4*)&As[kk][ty * 8 + 4];
            *(float4*)(bf)     = *(const float4*)&Bs[kk][tx * 8];
            *(float4*)(bf + 4) = *(const float4*)&Bs[kk][tx * 8 + 4];
#pragma unroll
            for (int i = 0; i < 8; ++i)
#pragma unroll
                for (int j = 0; j < 8; ++j)
                    acc[i][j] = fmaf(af[i], bf[j], acc[i][j]);
        }
    }
    // epilogue
    float bv[8];
    *(float4*)(bv)     = *(const float4*)&bias1[col0 + tx * 8];
    *(float4*)(bv + 4) = *(const float4*)&bias1[col0 + tx * 8 + 4];
    if (bias2) {
        float b2[8];
        *(float4*)(b2)     = *(const float4*)&bias2[col0 + tx * 8];
        *(float4*)(b2 + 4) = *(const float4*)&bias2[col0 + tx * 8 + 4];
#pragma unroll
        for (int j = 0; j < 8; ++j) bv[j] += b2[j];
    }
#pragma unroll
    for (int i = 0; i < 8; ++i) {
        int m = row0 + ty * 8 + i;
        float o[8];
#pragma unroll
        for (int j = 0; j < 8; ++j) {
            float v = acc[i][j] + bv[j];
            o[j] = relu ? fmaxf(v, 0.f) : v;
        }
        *(float4*)&O[(size_t)m * N + col0 + tx * 8]     = *(float4*)(o);
        *(float4*)&O[(size_t)m * N + col0 + tx * 8 + 4] = *(float4*)(o + 4);
    }
}

// ---------------- k_lstm: persistent sequential scan, barrier-free ----------------
// htag[2][HID] slots: (tag<<32)|float_bits, agent-scope atomics (coherent across XCDs).
// Step s: reads parity (s+1)&1 expecting tag s; writes parity s&1 with tag s+1.
// Safety of the 2-deep parity pipeline (per-wave): a wave stores tag s+2 into
// parity (s+1)&1 only after passing its step-(s+1) poll, which requires ALL 1024
// tag-(s+1) slots -> every wave in the device has passed (and thus finished
// reading) its step-s poll. No reader can observe the overwrite early.
__global__ __launch_bounds__(256, 1) void k_lstm(
    const float* __restrict__ Whh,     // [4096][1024]
    const float* __restrict__ Gin,     // [2048][4096] precomputed input-gate terms
    unsigned long long* __restrict__ htag)
{
    const int b    = blockIdx.x;    // 0..127, owns units [8b, 8b+8)
    const int t    = threadIdx.x;   // 0..255
    const int lane = t & 63;
    const int wv   = t >> 6;        // wave id 0..3 — waves fully independent

    // W_hh fragment: 8 rows (wv+4i), cols [lane*16, lane*16+16). Register-resident
    // (compiler allocates the 128 floats across VGPR/AGPR unified file).
    float w[8][16];
    int grow[8];
#pragma unroll
    for (int i = 0; i < 8; ++i) {
        int r = wv + 4 * i;
        grow[i] = ((r >> 3) << 10) + (b << 3) + (r & 7);
        const float4* p4 = (const float4*)(Whh + (size_t)grow[i] * HID + lane * 16);
#pragma unroll
        for (int q = 0; q < 4; ++q) {
            float4 a = p4[q];
            w[i][4 * q + 0] = a.x; w[i][4 * q + 1] = a.y;
            w[i][4 * q + 2] = a.z; w[i][4 * q + 3] = a.w;
        }
    }

    // Cell state for this wave's units {wv, wv+4}; lane-redundant (deterministic:
    // every lane computes identical post-butterfly sums).
    float c0 = 0.f, c1 = 0.f;
    unsigned long long* base = htag + 16 * lane;   // this thread's h-strip slots

    for (int s = 0; s < SEQ; ++s) {
        // Gin for this wave's 8 rows — same address across all 64 lanes
        // (HW broadcast, one transaction per value); issued before the poll so
        // the latency hides under it.
        float gv[8];
#pragma unroll
        for (int i = 0; i < 8; ++i) gv[i] = Gin[(size_t)s * G4 + grow[i]];

        // poll the 16 h values THIS thread needs: h[16*lane .. 16*lane+16)
        unsigned long long* src = base + (size_t)(((unsigned)(s + 1)) & 1u) * HID;
        const unsigned expw = (unsigned)s;
        unsigned long long v[16];
        for (;;) {
#pragma unroll
            for (int j = 0; j < 16; ++j)
                v[j] = __hip_atomic_load(src + j, __ATOMIC_RELAXED, __HIP_MEMORY_SCOPE_AGENT);
            int ok = 1;
#pragma unroll
            for (int j = 0; j < 16; ++j) ok &= ((unsigned)(v[j] >> 32) == expw);
            if (__all(ok)) break;
        }

        float hf[16];
#pragma unroll
        for (int j = 0; j < 16; ++j) hf[j] = __uint_as_float((unsigned)v[j]);

        // per-lane partial dot over this lane's 16 columns
        float p[8];
#pragma unroll
        for (int i = 0; i < 8; ++i) p[i] = 0.f;
#pragma unroll
        for (int j = 0; j < 16; ++j)
#pragma unroll
            for (int i = 0; i < 8; ++i)
                p[i] = fmaf(w[i][j], hf[j], p[i]);

        // 64-lane butterfly: every lane ends with the full row sums
#pragma unroll
        for (int off = 1; off < 64; off <<= 1)
#pragma unroll
            for (int i = 0; i < 8; ++i)
                p[i] += __shfl_xor(p[i], off);

        // add input-gate terms once per lane-local copy
#pragma unroll
        for (int i = 0; i < 8; ++i) p[i] += gv[i];

        // unit u=wv   : gates i,f,g,o = p[0],p[2],p[4],p[6]
        // unit u=wv+4 : gates i,f,g,o = p[1],p[3],p[5],p[7]
        float cn0 = fsig(p[2]) * c0 + fsig(p[0]) * ftanh(p[4]);
        float cn1 = fsig(p[3]) * c1 + fsig(p[1]) * ftanh(p[5]);
        c0 = cn0; c1 = cn1;
        float h0 = fsig(p[6]) * ftanh(cn0);
        float h1 = fsig(p[7]) * ftanh(cn1);

        unsigned long long tagw = ((unsigned long long)(unsigned)(s + 1) << 32);
        unsigned long long* dst =
            htag + (size_t)(((unsigned)s) & 1u) * HID + b * 8 + wv;
        if (lane == 0)
            __hip_atomic_store(dst, tagw | __float_as_uint(h0),
                               __ATOMIC_RELAXED, __HIP_MEMORY_SCOPE_AGENT);
        else if (lane == 1)
            __hip_atomic_store(dst + 4, tagw | __float_as_uint(h1),
                               __ATOMIC_RELAXED, __HIP_MEMORY_SCOPE_AGENT);
    }
}

// ---------------- k_out: out = out_W @ h_final + out_b ----------------
__global__ void k_out(const float* __restrict__ outW,
                      const float* __restrict__ outb,
                      const unsigned long long* __restrict__ htag,
                      float* __restrict__ out)
{
    int wv = threadIdx.x >> 6, lane = threadIdx.x & 63;   // 7 waves
    if (wv < NLAB) {
        float s = 0.f;
        for (int k = lane; k < HID; k += 64) {
            float h = __uint_as_float((unsigned)(htag[HID + k] & 0xffffffffULL));
            s = fmaf(outW[wv * HID + k], h, s);
        }
#pragma unroll
        for (int off = 1; off < 64; off <<= 1) s += __shfl_xor(s, off);
        if (lane == 0) out[wv] = s + outb[wv];
    }
}

extern "C" void kernel_launch(void* const* d_in, const int* in_sizes, int n_in,
                              void* d_out, int out_size, void* d_ws, size_t ws_size,
                              hipStream_t stream)
{
    const int*   sent_ids = (const int*)  d_in[0];
    const int*   emo_ids  = (const int*)  d_in[1];
    const float* word_emb = (const float*)d_in[2];
    const float* emo_emb  = (const float*)d_in[3];
    // d_in[4] attn_W, d_in[5] attn_b: unused — softmax over a single logit == 1.0
    const float* comb_W   = (const float*)d_in[6];
    const float* comb_b   = (const float*)d_in[7];
    const float* W_ih     = (const float*)d_in[8];
    const float* W_hh     = (const float*)d_in[9];
    const float* b_ih     = (const float*)d_in[10];
    const float* b_hh     = (const float*)d_in[11];
    const float* out_W    = (const float*)d_in[12];
    const float* out_b    = (const float*)d_in[13];
    float* out = (float*)d_out;

    float* ws   = (float*)d_ws;
    float* eave = ws;                                   // 1024
    float* cvec = ws + 1024;                            // 1024 (pad to 4096)
    float* C    = ws + 4096;                            // 2048*1024
    float* G    = ws + 4096 + (size_t)SEQ * EMB;        // 2048*4096
    unsigned long long* htag =
        (unsigned long long*)(ws + 4096 + (size_t)SEQ * EMB + (size_t)SEQ * G4); // 2*1024 u64

    k_init<<<1, 256, 0, stream>>>(emo_ids, emo_emb, eave, htag);
    k_cvec<<<64, 256, 0, stream>>>(comb_W, comb_b, eave, cvec);
    // C = relu( gather(word_emb, sent_ids) @ W_x^T + cvec ),  W_x = comb_W[:, :1024]
    dim3 g1(EMB / 128, SEQ / 128);
    k_gemm<<<g1, 256, 0, stream>>>(nullptr, sent_ids, word_emb,
                                   comb_W, 2048, cvec, nullptr, C, EMB, 1);
    // G = C @ W_ih^T + b_ih + b_hh
    dim3 g2(G4 / 128, SEQ / 128);
    k_gemm<<<g2, 256, 0, stream>>>(C, nullptr, nullptr,
                                   W_ih, 1024, b_ih, b_hh, G, G4, 0);
    k_lstm<<<NB, 256, 0, stream>>>(W_hh, G, htag);
    k_out<<<1, 448, 0, stream>>>(out_W, out_b, htag, out);
}

// Round 3
// 8232.594 us; speedup vs baseline: 2.8698x; 2.8698x over previous
//
#include <hip/hip_runtime.h>
#include <hip/hip_bf16.h>
#include <stdint.h>
#include <math.h>

// Problem constants (fixed by the reference)
#define SEQ    2048
#define EMB    1024
#define HID    1024
#define G4     4096      // 4*HID
#define NEMO   16
#define NLAB   7

// LSTM persistent-kernel partition: 128 blocks x 256 threads (4 waves).
// Block b owns units [8b, 8b+8). Local row r = gate*8 + (u&7); wave wv = r&3
// owns rows {wv, wv+4, ..., wv+28} = ALL 4 gates of units {wv, wv+4} -> after
// one h-staging barrier the rest of the step is wave-local (butterfly + tail).
#define NB 128

// htag geometry: [2 parities][128 blocks][16 u64] -- 8 live slots + 8 pad so
// each writer block owns a full 128-B line (blocks land on different XCDs;
// unpadded, blocks 2k/2k+1 false-share one line at the coherence point).
#define HSTRIDE 16
#define HPAR    (NB * HSTRIDE)   // 2048 u64 per parity

// Fast branch-free sigmoid/tanh (v_exp_f32 + v_rcp_f32).
__device__ __forceinline__ float fsig(float x) {
    return __builtin_amdgcn_rcpf(1.0f + __builtin_amdgcn_exp2f(x * -1.4426950408889634f));
}
__device__ __forceinline__ float ftanh(float x) {
    // tanh(x) = 2*sigmoid(2x) - 1 ; exp2 under/overflow saturates correctly.
    return 2.0f * __builtin_amdgcn_rcpf(1.0f + __builtin_amdgcn_exp2f(x * -2.8853900817779268f)) - 1.0f;
}

// ---------------- k_init: emoji average + htag reset ----------------
__global__ void k_init(const int* __restrict__ emoji_ids,
                       const float* __restrict__ emoji_emb,
                       float* __restrict__ eave,
                       unsigned long long* __restrict__ htag)
{
    int t = threadIdx.x;
    int ids[NEMO];
#pragma unroll
    for (int n = 0; n < NEMO; ++n) ids[n] = emoji_ids[n];
    for (int e = t; e < EMB; e += 256) {
        float s = 0.f;
#pragma unroll
        for (int n = 0; n < NEMO; ++n) s += emoji_emb[(size_t)ids[n] * EMB + e];
        eave[e] = s * (1.0f / 16.0f);
    }
    // htag[2][NB][16]: tag=0, value=0.0f  (h_{-1} = zeros in both parities)
    for (int i = t; i < 2 * HPAR; i += 256) htag[i] = 0ull;
}

// ---------------- k_cvec: cvec = comb_W[:,1024:] @ eave + comb_b ----------------
__global__ void k_cvec(const float* __restrict__ combW,
                       const float* __restrict__ combB,
                       const float* __restrict__ eave,
                       float* __restrict__ cvec)
{
    // 64 blocks x 256 threads = 256 waves; 4 rows per wave
    int gw   = (blockIdx.x * 256 + threadIdx.x) >> 6;
    int lane = threadIdx.x & 63;
#pragma unroll
    for (int rr = 0; rr < 4; ++rr) {
        int r = gw * 4 + rr;
        const float* wrow = combW + (size_t)r * 2048 + 1024;
        float s = 0.f;
        for (int k = lane; k < EMB; k += 64) s = fmaf(wrow[k], eave[k], s);
#pragma unroll
        for (int off = 1; off < 64; off <<= 1) s += __shfl_xor(s, off);
        if (lane == 0) cvec[r] = s + combB[r];
    }
}

// ---------------- k_gemm: O[m][n] = sum_k Arow(m)[k]*B[n*bstride+k] + bias (+relu) ----
// BM=BN=128, BK=16, 256 threads, 8x8 microtile. K fixed at 1024, dims divide evenly.
__global__ __launch_bounds__(256) void k_gemm(
    const float* __restrict__ Asrc,
    const int*   __restrict__ ids,       // if non-null: A row m = emb[ids[m]]
    const float* __restrict__ emb,
    const float* __restrict__ B, int bstride,
    const float* __restrict__ bias1,
    const float* __restrict__ bias2,     // optional second bias
    float* __restrict__ O, int N, int relu)
{
    __shared__ float As[16][128];
    __shared__ float Bs[16][128];
    const int tid  = threadIdx.x;
    const int row0 = blockIdx.y * 128;
    const int col0 = blockIdx.x * 128;
    const int lr = tid >> 2;     // 0..63: staging row
    const int kq = tid & 3;      // 0..3 : k quad
    const float *ar0, *ar1;
    if (ids) {
        ar0 = emb + (size_t)ids[row0 + lr]      * 1024;
        ar1 = emb + (size_t)ids[row0 + lr + 64] * 1024;
    } else {
        ar0 = Asrc + (size_t)(row0 + lr)      * 1024;
        ar1 = Asrc + (size_t)(row0 + lr + 64) * 1024;
    }
    const float* br0 = B + (size_t)(col0 + lr)      * bstride;
    const float* br1 = B + (size_t)(col0 + lr + 64) * bstride;
    const int tx = tid & 15, ty = tid >> 4;

    float acc[8][8];
#pragma unroll
    for (int i = 0; i < 8; ++i)
#pragma unroll
        for (int j = 0; j < 8; ++j) acc[i][j] = 0.f;

    for (int k0 = 0; k0 < 1024; k0 += 16) {
        float4 a0 = *(const float4*)(ar0 + k0 + kq * 4);
        float4 a1 = *(const float4*)(ar1 + k0 + kq * 4);
        float4 b0 = *(const float4*)(br0 + k0 + kq * 4);
        float4 b1 = *(const float4*)(br1 + k0 + kq * 4);
        __syncthreads();
        {
            const float* pa0 = &a0.x; const float* pa1 = &a1.x;
            const float* pb0 = &b0.x; const float* pb1 = &b1.x;
#pragma unroll
            for (int e = 0; e < 4; ++e) {
                As[kq * 4 + e][lr]      = pa0[e];
                As[kq * 4 + e][lr + 64] = pa1[e];
                Bs[kq * 4 + e][lr]      = pb0[e];
                Bs[kq * 4 + e][lr + 64] = pb1[e];
            }
        }
        __syncthreads();
#pragma unroll
        for (int kk = 0; kk < 16; ++kk) {
            float af[8], bf[8];
            *(float4*)(af)     = *(const float4*)&As[kk][ty * 8];
            *(float4*)(af + 4) = *(const float4*)&As[kk][ty * 8 + 4];
            *(float4*)(bf)     = *(const float4*)&Bs[kk][tx * 8];
            *(float4*)(bf + 4) = *(const float4*)&Bs[kk][tx * 8 + 4];
#pragma unroll
            for (int i = 0; i < 8; ++i)
#pragma unroll
                for (int j = 0; j < 8; ++j)
                    acc[i][j] = fmaf(af[i], bf[j], acc[i][j]);
        }
    }
    // epilogue
    float bv[8];
    *(float4*)(bv)     = *(const float4*)&bias1[col0 + tx * 8];
    *(float4*)(bv + 4) = *(const float4*)&bias1[col0 + tx * 8 + 4];
    if (bias2) {
        float b2[8];
        *(float4*)(b2)     = *(const float4*)&bias2[col0 + tx * 8];
        *(float4*)(b2 + 4) = *(const float4*)&bias2[col0 + tx * 8 + 4];
#pragma unroll
        for (int j = 0; j < 8; ++j) bv[j] += b2[j];
    }
#pragma unroll
    for (int i = 0; i < 8; ++i) {
        int m = row0 + ty * 8 + i;
        float o[8];
#pragma unroll
        for (int j = 0; j < 8; ++j) {
            float v = acc[i][j] + bv[j];
            o[j] = relu ? fmaxf(v, 0.f) : v;
        }
        *(float4*)&O[(size_t)m * N + col0 + tx * 8]     = *(float4*)(o);
        *(float4*)&O[(size_t)m * N + col0 + tx * 8 + 4] = *(float4*)(o + 4);
    }
}

// ---------------- k_lstm: persistent scan, 1 barrier/step ----------------
// Slots: (tag<<32)|float_bits, agent-scope relaxed atomics (self-verifying —
// no release/acquire fences needed). Step s: reads parity (s+1)&1 expecting
// tag s; writes parity s&1 with tag s+1.
// 2-deep pipeline safety: a wave stores tag s+1 into parity s&1 only after the
// S1 barrier of step s, i.e. after ALL 1024 tag-s slots were observed -> every
// wave device-wide finished its step-(s-1) reads of parity s&1. No early
// overwrite. LDS hl4 reuse is protected by the same argument + the barrier.
__global__ __launch_bounds__(256, 1) void k_lstm(
    const float* __restrict__ Whh,     // [4096][1024]
    const float* __restrict__ Gin,     // [2048][4096] precomputed input-gate terms
    unsigned long long* __restrict__ htag)
{
    const int b    = blockIdx.x;    // 0..127, owns units [8b, 8b+8)
    const int t    = threadIdx.x;   // 0..255
    const int lane = t & 63;
    const int wv   = t >> 6;        // wave id 0..3

    // W_hh fragment: 8 rows (wv+4i), cols [lane*16, lane*16+16). Register-resident.
    float w[8][16];
    int grow[8];
#pragma unroll
    for (int i = 0; i < 8; ++i) {
        int r = wv + 4 * i;
        grow[i] = ((r >> 3) << 10) + (b << 3) + (r & 7);
        const float4* p4 = (const float4*)(Whh + (size_t)grow[i] * HID + lane * 16);
#pragma unroll
        for (int q = 0; q < 4; ++q) {
            float4 a = p4[q];
            w[i][4 * q + 0] = a.x; w[i][4 * q + 1] = a.y;
            w[i][4 * q + 2] = a.z; w[i][4 * q + 3] = a.w;
        }
    }

    __shared__ float4 hl4[256];   // h staged: hl4[q*64 + col] = h[col*16+q*4 ..+4)

    // Poll slots for this thread: h indices 4t..4t+3 = block t>>1, units (t&1)*4..+4
    unsigned long long* myslots = htag + (t >> 1) * HSTRIDE + (t & 1) * 4;
    // Cell state for this wave's units {wv, wv+4}; lane-redundant & deterministic.
    float c0 = 0.f, c1 = 0.f;

    for (int s = 0; s < SEQ; ++s) {
        // Gin for this wave's 8 rows — wave-uniform addresses (HW broadcast,
        // 1 transaction each); issued before the poll so HBM latency hides.
        float gv[8];
#pragma unroll
        for (int i = 0; i < 8; ++i) gv[i] = Gin[(size_t)s * G4 + grow[i]];

        // poll h_{s-1}: 4 tagged slots per thread, predicated re-poll
        unsigned long long* src = myslots + (size_t)(((unsigned)(s + 1)) & 1u) * HPAR;
        const unsigned expw = (unsigned)s;
        unsigned long long v0 = 0, v1 = 0, v2 = 0, v3 = 0;
        int done = 0;
        for (;;) {
            if (!done) {
                v0 = __hip_atomic_load(src + 0, __ATOMIC_RELAXED, __HIP_MEMORY_SCOPE_AGENT);
                v1 = __hip_atomic_load(src + 1, __ATOMIC_RELAXED, __HIP_MEMORY_SCOPE_AGENT);
                v2 = __hip_atomic_load(src + 2, __ATOMIC_RELAXED, __HIP_MEMORY_SCOPE_AGENT);
                v3 = __hip_atomic_load(src + 3, __ATOMIC_RELAXED, __HIP_MEMORY_SCOPE_AGENT);
                done = ((unsigned)(v0 >> 32) == expw) & ((unsigned)(v1 >> 32) == expw) &
                       ((unsigned)(v2 >> 32) == expw) & ((unsigned)(v3 >> 32) == expw);
            }
            if (__all(done)) break;
        }
        hl4[(t & 3) * 64 + (t >> 2)] = make_float4(
            __uint_as_float((unsigned)v0), __uint_as_float((unsigned)v1),
            __uint_as_float((unsigned)v2), __uint_as_float((unsigned)v3));
        __syncthreads();   // S1: full h staged (only barrier in the step)

        float hf[16];
#pragma unroll
        for (int q = 0; q < 4; ++q) {
            float4 hv = hl4[q * 64 + lane];
            hf[4 * q + 0] = hv.x; hf[4 * q + 1] = hv.y;
            hf[4 * q + 2] = hv.z; hf[4 * q + 3] = hv.w;
        }

        // per-lane partial dot over this lane's 16 columns
        float p[8];
#pragma unroll
        for (int i = 0; i < 8; ++i) p[i] = 0.f;
#pragma unroll
        for (int j = 0; j < 16; ++j)
#pragma unroll
            for (int i = 0; i < 8; ++i)
                p[i] = fmaf(w[i][j], hf[j], p[i]);

        // 64-lane butterfly: every lane ends with full row sums
#pragma unroll
        for (int off = 1; off < 64; off <<= 1)
#pragma unroll
            for (int i = 0; i < 8; ++i)
                p[i] += __shfl_xor(p[i], off);

#pragma unroll
        for (int i = 0; i < 8; ++i) p[i] += gv[i];

        // unit wv   : i,f,g,o = p[0],p[2],p[4],p[6]
        // unit wv+4 : i,f,g,o = p[1],p[3],p[5],p[7]
        float cn0 = fsig(p[2]) * c0 + fsig(p[0]) * ftanh(p[4]);
        float cn1 = fsig(p[3]) * c1 + fsig(p[1]) * ftanh(p[5]);
        c0 = cn0; c1 = cn1;
        float h0 = fsig(p[6]) * ftanh(cn0);
        float h1 = fsig(p[7]) * ftanh(cn1);

        unsigned long long tagw = ((unsigned long long)(unsigned)(s + 1) << 32);
        unsigned long long* dst =
            htag + (size_t)(((unsigned)s) & 1u) * HPAR + b * HSTRIDE + wv;
        if (lane == 0)
            __hip_atomic_store(dst, tagw | __float_as_uint(h0),
                               __ATOMIC_RELAXED, __HIP_MEMORY_SCOPE_AGENT);
        else if (lane == 1)
            __hip_atomic_store(dst + 4, tagw | __float_as_uint(h1),
                               __ATOMIC_RELAXED, __HIP_MEMORY_SCOPE_AGENT);
    }
}

// ---------------- k_out: out = out_W @ h_final + out_b ----------------
__global__ void k_out(const float* __restrict__ outW,
                      const float* __restrict__ outb,
                      const unsigned long long* __restrict__ htag,
                      float* __restrict__ out)
{
    int wv = threadIdx.x >> 6, lane = threadIdx.x & 63;   // 7 waves
    if (wv < NLAB) {
        float s = 0.f;
        for (int k = lane; k < HID; k += 64) {
            // final h is at parity 1 (last step s=2047)
            unsigned long long v = htag[HPAR + (k >> 3) * HSTRIDE + (k & 7)];
            float h = __uint_as_float((unsigned)(v & 0xffffffffULL));
            s = fmaf(outW[wv * HID + k], h, s);
        }
#pragma unroll
        for (int off = 1; off < 64; off <<= 1) s += __shfl_xor(s, off);
        if (lane == 0) out[wv] = s + outb[wv];
    }
}

extern "C" void kernel_launch(void* const* d_in, const int* in_sizes, int n_in,
                              void* d_out, int out_size, void* d_ws, size_t ws_size,
                              hipStream_t stream)
{
    const int*   sent_ids = (const int*)  d_in[0];
    const int*   emo_ids  = (const int*)  d_in[1];
    const float* word_emb = (const float*)d_in[2];
    const float* emo_emb  = (const float*)d_in[3];
    // d_in[4] attn_W, d_in[5] attn_b: unused — softmax over a single logit == 1.0
    const float* comb_W   = (const float*)d_in[6];
    const float* comb_b   = (const float*)d_in[7];
    const float* W_ih     = (const float*)d_in[8];
    const float* W_hh     = (const float*)d_in[9];
    const float* b_ih     = (const float*)d_in[10];
    const float* b_hh     = (const float*)d_in[11];
    const float* out_W    = (const float*)d_in[12];
    const float* out_b    = (const float*)d_in[13];
    float* out = (float*)d_out;

    float* ws   = (float*)d_ws;
    float* eave = ws;                                   // 1024
    float* cvec = ws + 1024;                            // 1024 (pad to 4096)
    float* C    = ws + 4096;                            // 2048*1024
    float* G    = ws + 4096 + (size_t)SEQ * EMB;        // 2048*4096
    unsigned long long* htag =
        (unsigned long long*)(ws + 4096 + (size_t)SEQ * EMB + (size_t)SEQ * G4); // 2*HPAR u64

    k_init<<<1, 256, 0, stream>>>(emo_ids, emo_emb, eave, htag);
    k_cvec<<<64, 256, 0, stream>>>(comb_W, comb_b, eave, cvec);
    // C = relu( gather(word_emb, sent_ids) @ W_x^T + cvec ),  W_x = comb_W[:, :1024]
    dim3 g1(EMB / 128, SEQ / 128);
    k_gemm<<<g1, 256, 0, stream>>>(nullptr, sent_ids, word_emb,
                                   comb_W, 2048, cvec, nullptr, C, EMB, 1);
    // G = C @ W_ih^T + b_ih + b_hh
    dim3 g2(G4 / 128, SEQ / 128);
    k_gemm<<<g2, 256, 0, stream>>>(C, nullptr, nullptr,
                                   W_ih, 1024, b_ih, b_hh, G, G4, 0);
    k_lstm<<<NB, 256, 0, stream>>>(W_hh, G, htag);
    k_out<<<1, 448, 0, stream>>>(out_W, out_b, htag, out);
}

// Round 4
// 5694.483 us; speedup vs baseline: 4.1489x; 1.4457x over previous
//
#include <hip/hip_runtime.h>
#include <hip/hip_bf16.h>
#include <stdint.h>
#include <math.h>

// Problem constants (fixed by the reference)
#define SEQ    2048
#define EMB    1024
#define HID    1024
#define G4     4096      // 4*HID
#define NEMO   16
#define NLAB   7

// LSTM persistent-kernel partition: 64 blocks x 512 threads (8 waves).
// Block b owns units [16b, 16b+16)  ->  its 16 h-slots are EXACTLY one 128-B
// line (dense layout), stored by ONE 16-lane instruction: no false sharing,
// no multi-wave same-line serialization at the coherence point (round-3 killer).
// Wave wv owns local rows {wv+8i} = all 4 gates of units {wv, wv+8}: after one
// h-staging barrier the matvec+butterfly+gate-tail is wave-local.
#define NB 64

// Fast branch-free sigmoid/tanh (v_exp_f32 + v_rcp_f32).
__device__ __forceinline__ float fsig(float x) {
    return __builtin_amdgcn_rcpf(1.0f + __builtin_amdgcn_exp2f(x * -1.4426950408889634f));
}
__device__ __forceinline__ float ftanh(float x) {
    // tanh(x) = 2*sigmoid(2x) - 1 ; exp2 under/overflow saturates correctly.
    return 2.0f * __builtin_amdgcn_rcpf(1.0f + __builtin_amdgcn_exp2f(x * -2.8853900817779268f)) - 1.0f;
}

// ---------------- k_init: emoji average + htag reset ----------------
__global__ void k_init(const int* __restrict__ emoji_ids,
                       const float* __restrict__ emoji_emb,
                       float* __restrict__ eave,
                       unsigned long long* __restrict__ htag)
{
    int t = threadIdx.x;
    int ids[NEMO];
#pragma unroll
    for (int n = 0; n < NEMO; ++n) ids[n] = emoji_ids[n];
    for (int e = t; e < EMB; e += 256) {
        float s = 0.f;
#pragma unroll
        for (int n = 0; n < NEMO; ++n) s += emoji_emb[(size_t)ids[n] * EMB + e];
        eave[e] = s * (1.0f / 16.0f);
    }
    // htag[2][HID]: tag=0, value=0.0f  (h_{-1} = zeros, both parities)
    for (int i = t; i < 2 * HID; i += 256) htag[i] = 0ull;
}

// ---------------- k_cvec: cvec = comb_W[:,1024:] @ eave + comb_b ----------------
__global__ void k_cvec(const float* __restrict__ combW,
                       const float* __restrict__ combB,
                       const float* __restrict__ eave,
                       float* __restrict__ cvec)
{
    // 64 blocks x 256 threads = 256 waves; 4 rows per wave
    int gw   = (blockIdx.x * 256 + threadIdx.x) >> 6;
    int lane = threadIdx.x & 63;
#pragma unroll
    for (int rr = 0; rr < 4; ++rr) {
        int r = gw * 4 + rr;
        const float* wrow = combW + (size_t)r * 2048 + 1024;
        float s = 0.f;
        for (int k = lane; k < EMB; k += 64) s = fmaf(wrow[k], eave[k], s);
#pragma unroll
        for (int off = 1; off < 64; off <<= 1) s += __shfl_xor(s, off);
        if (lane == 0) cvec[r] = s + combB[r];
    }
}

// ---------------- k_gemm: O[m][n] = sum_k Arow(m)[k]*B[n*bstride+k] + bias (+relu) ----
// BM=BN=128, BK=16, 256 threads, 8x8 microtile. K fixed at 1024, dims divide evenly.
__global__ __launch_bounds__(256) void k_gemm(
    const float* __restrict__ Asrc,
    const int*   __restrict__ ids,       // if non-null: A row m = emb[ids[m]]
    const float* __restrict__ emb,
    const float* __restrict__ B, int bstride,
    const float* __restrict__ bias1,
    const float* __restrict__ bias2,     // optional second bias
    float* __restrict__ O, int N, int relu)
{
    __shared__ float As[16][128];
    __shared__ float Bs[16][128];
    const int tid  = threadIdx.x;
    const int row0 = blockIdx.y * 128;
    const int col0 = blockIdx.x * 128;
    const int lr = tid >> 2;     // 0..63: staging row
    const int kq = tid & 3;      // 0..3 : k quad
    const float *ar0, *ar1;
    if (ids) {
        ar0 = emb + (size_t)ids[row0 + lr]      * 1024;
        ar1 = emb + (size_t)ids[row0 + lr + 64] * 1024;
    } else {
        ar0 = Asrc + (size_t)(row0 + lr)      * 1024;
        ar1 = Asrc + (size_t)(row0 + lr + 64) * 1024;
    }
    const float* br0 = B + (size_t)(col0 + lr)      * bstride;
    const float* br1 = B + (size_t)(col0 + lr + 64) * bstride;
    const int tx = tid & 15, ty = tid >> 4;

    float acc[8][8];
#pragma unroll
    for (int i = 0; i < 8; ++i)
#pragma unroll
        for (int j = 0; j < 8; ++j) acc[i][j] = 0.f;

    for (int k0 = 0; k0 < 1024; k0 += 16) {
        float4 a0 = *(const float4*)(ar0 + k0 + kq * 4);
        float4 a1 = *(const float4*)(ar1 + k0 + kq * 4);
        float4 b0 = *(const float4*)(br0 + k0 + kq * 4);
        float4 b1 = *(const float4*)(br1 + k0 + kq * 4);
        __syncthreads();
        {
            const float* pa0 = &a0.x; const float* pa1 = &a1.x;
            const float* pb0 = &b0.x; const float* pb1 = &b1.x;
#pragma unroll
            for (int e = 0; e < 4; ++e) {
                As[kq * 4 + e][lr]      = pa0[e];
                As[kq * 4 + e][lr + 64] = pa1[e];
                Bs[kq * 4 + e][lr]      = pb0[e];
                Bs[kq * 4 + e][lr + 64] = pb1[e];
            }
        }
        __syncthreads();
#pragma unroll
        for (int kk = 0; kk < 16; ++kk) {
            float af[8], bf[8];
            *(float4*)(af)     = *(const float4*)&As[kk][ty * 8];
            *(float4*)(af + 4) = *(const float4*)&As[kk][ty * 8 + 4];
            *(float4*)(bf)     = *(const float4*)&Bs[kk][tx * 8];
            *(float4*)(bf + 4) = *(const float4*)&Bs[kk][tx * 8 + 4];
#pragma unroll
            for (int i = 0; i < 8; ++i)
#pragma unroll
                for (int j = 0; j < 8; ++j)
                    acc[i][j] = fmaf(af[i], bf[j], acc[i][j]);
        }
    }
    // epilogue
    float bv[8];
    *(float4*)(bv)     = *(const float4*)&bias1[col0 + tx * 8];
    *(float4*)(bv + 4) = *(const float4*)&bias1[col0 + tx * 8 + 4];
    if (bias2) {
        float b2[8];
        *(float4*)(b2)     = *(const float4*)&bias2[col0 + tx * 8];
        *(float4*)(b2 + 4) = *(const float4*)&bias2[col0 + tx * 8 + 4];
#pragma unroll
        for (int j = 0; j < 8; ++j) bv[j] += b2[j];
    }
#pragma unroll
    for (int i = 0; i < 8; ++i) {
        int m = row0 + ty * 8 + i;
        float o[8];
#pragma unroll
        for (int j = 0; j < 8; ++j) {
            float v = acc[i][j] + bv[j];
            o[j] = relu ? fmaxf(v, 0.f) : v;
        }
        *(float4*)&O[(size_t)m * N + col0 + tx * 8]     = *(float4*)(o);
        *(float4*)&O[(size_t)m * N + col0 + tx * 8 + 4] = *(float4*)(o + 4);
    }
}

// ---------------- k_lstm: persistent scan, 64 blocks x 512 threads ----------------
// Slots: (tag<<32)|float_bits, agent-scope relaxed atomics, dense htag[2][1024].
// Step s: reads parity (s+1)&1 expecting tag s; writes parity s&1 with tag s+1.
// 2-deep pipeline safety: a block stores tag s+1 only after its step-s poll saw
// all 1024 tag-s slots -> every block device-wide completed its step-(s-1)
// reads of parity s&1 (reads precede that block's step-(s-1) store by data +
// barrier dependencies). No early overwrite. hout race-freedom: any wave's
// step-(s+1) hout write is gated by poll(s+1), which requires THIS block's
// wave-0 store, which follows wave-0's hout reads.
__global__ __launch_bounds__(512, 1) void k_lstm(
    const float* __restrict__ Whh,     // [4096][1024]
    const float* __restrict__ Gin,     // [2048][4096] precomputed input-gate terms
    unsigned long long* __restrict__ htag)
{
    const int b    = blockIdx.x;    // 0..63, owns units [16b, 16b+16)
    const int t    = threadIdx.x;   // 0..511
    const int lane = t & 63;
    const int wv   = t >> 6;        // wave id 0..7

    // Local rows r = wv + 8i, i=0..7 -> (gate, unit_local) = (i>>1, wv + (i&1)*8).
    // Global row = gate*1024 + 16b + unit_local. Fragment: 8 rows x 16 cols.
    float w[8][16];
    int grow[8];
#pragma unroll
    for (int i = 0; i < 8; ++i) {
        grow[i] = ((i >> 1) << 10) + (b << 4) + wv + ((i & 1) << 3);
        const float4* p4 = (const float4*)(Whh + (size_t)grow[i] * HID + lane * 16);
#pragma unroll
        for (int q = 0; q < 4; ++q) {
            float4 a = p4[q];
            w[i][4 * q + 0] = a.x; w[i][4 * q + 1] = a.y;
            w[i][4 * q + 2] = a.z; w[i][4 * q + 3] = a.w;
        }
    }

    __shared__ float hl[1024];    // staged h
    __shared__ float hout[16];    // this block's new h values

    unsigned long long* myslots = htag + 2 * t;   // +parity*HID at use
    // Cell state for this wave's units {wv, wv+8}; lane-redundant & deterministic.
    float c0 = 0.f, c1 = 0.f;

    for (int s = 0; s < SEQ; ++s) {
        // Gin for this wave's 8 rows — wave-uniform addresses (HW broadcast);
        // issued before the poll so HBM latency hides under it.
        float gv[8];
#pragma unroll
        for (int i = 0; i < 8; ++i) gv[i] = Gin[(size_t)s * G4 + grow[i]];

        // poll h_{s-1}: 2 tagged slots per thread (dense, contiguous 16 B)
        unsigned long long* src = myslots + (size_t)(((unsigned)(s + 1)) & 1u) * HID;
        const unsigned expw = (unsigned)s;
        unsigned long long v0, v1;
        for (;;) {
            v0 = __hip_atomic_load(src + 0, __ATOMIC_RELAXED, __HIP_MEMORY_SCOPE_AGENT);
            v1 = __hip_atomic_load(src + 1, __ATOMIC_RELAXED, __HIP_MEMORY_SCOPE_AGENT);
            int ok = ((unsigned)(v0 >> 32) == expw) & ((unsigned)(v1 >> 32) == expw);
            if (__all(ok)) break;
        }
        hl[2 * t]     = __uint_as_float((unsigned)v0);
        hl[2 * t + 1] = __uint_as_float((unsigned)v1);
        __syncthreads();   // S1: full h staged

        float hf[16];
#pragma unroll
        for (int q = 0; q < 4; ++q) {
            float4 hv = *(const float4*)&hl[lane * 16 + q * 4];
            hf[4 * q + 0] = hv.x; hf[4 * q + 1] = hv.y;
            hf[4 * q + 2] = hv.z; hf[4 * q + 3] = hv.w;
        }

        // per-lane partial dot over this lane's 16 columns
        float p[8];
#pragma unroll
        for (int i = 0; i < 8; ++i) p[i] = 0.f;
#pragma unroll
        for (int j = 0; j < 16; ++j)
#pragma unroll
            for (int i = 0; i < 8; ++i)
                p[i] = fmaf(w[i][j], hf[j], p[i]);

        // 64-lane butterfly: every lane ends with full row sums
#pragma unroll
        for (int off = 1; off < 64; off <<= 1)
#pragma unroll
            for (int i = 0; i < 8; ++i)
                p[i] += __shfl_xor(p[i], off);

#pragma unroll
        for (int i = 0; i < 8; ++i) p[i] += gv[i];

        // unit wv   : i,f,g,o = p[0],p[2],p[4],p[6]
        // unit wv+8 : i,f,g,o = p[1],p[3],p[5],p[7]
        float cn0 = fsig(p[2]) * c0 + fsig(p[0]) * ftanh(p[4]);
        float cn1 = fsig(p[3]) * c1 + fsig(p[1]) * ftanh(p[5]);
        c0 = cn0; c1 = cn1;
        float h0 = fsig(p[6]) * ftanh(cn0);
        float h1 = fsig(p[7]) * ftanh(cn1);

        if (lane == 0) { hout[wv] = h0; hout[wv + 8] = h1; }
        __syncthreads();   // S2: hout complete

        // ONE 16-lane store instruction covering the block's private 128-B line
        if (t < 16) {
            unsigned long long pk =
                ((unsigned long long)(unsigned)(s + 1) << 32) |
                (unsigned long long)__float_as_uint(hout[t]);
            __hip_atomic_store(htag + (size_t)(((unsigned)s) & 1u) * HID + (b << 4) + t,
                               pk, __ATOMIC_RELAXED, __HIP_MEMORY_SCOPE_AGENT);
        }
    }
}

// ---------------- k_out: out = out_W @ h_final + out_b ----------------
__global__ void k_out(const float* __restrict__ outW,
                      const float* __restrict__ outb,
                      const unsigned long long* __restrict__ htag,
                      float* __restrict__ out)
{
    int wv = threadIdx.x >> 6, lane = threadIdx.x & 63;   // 7 waves
    if (wv < NLAB) {
        float s = 0.f;
        for (int k = lane; k < HID; k += 64) {
            // final h is at parity 1 (last step s=2047)
            float h = __uint_as_float((unsigned)(htag[HID + k] & 0xffffffffULL));
            s = fmaf(outW[wv * HID + k], h, s);
        }
#pragma unroll
        for (int off = 1; off < 64; off <<= 1) s += __shfl_xor(s, off);
        if (lane == 0) out[wv] = s + outb[wv];
    }
}

extern "C" void kernel_launch(void* const* d_in, const int* in_sizes, int n_in,
                              void* d_out, int out_size, void* d_ws, size_t ws_size,
                              hipStream_t stream)
{
    const int*   sent_ids = (const int*)  d_in[0];
    const int*   emo_ids  = (const int*)  d_in[1];
    const float* word_emb = (const float*)d_in[2];
    const float* emo_emb  = (const float*)d_in[3];
    // d_in[4] attn_W, d_in[5] attn_b: unused — softmax over a single logit == 1.0
    const float* comb_W   = (const float*)d_in[6];
    const float* comb_b   = (const float*)d_in[7];
    const float* W_ih     = (const float*)d_in[8];
    const float* W_hh     = (const float*)d_in[9];
    const float* b_ih     = (const float*)d_in[10];
    const float* b_hh     = (const float*)d_in[11];
    const float* out_W    = (const float*)d_in[12];
    const float* out_b    = (const float*)d_in[13];
    float* out = (float*)d_out;

    float* ws   = (float*)d_ws;
    float* eave = ws;                                   // 1024
    float* cvec = ws + 1024;                            // 1024 (pad to 4096)
    float* C    = ws + 4096;                            // 2048*1024
    float* G    = ws + 4096 + (size_t)SEQ * EMB;        // 2048*4096
    unsigned long long* htag =
        (unsigned long long*)(ws + 4096 + (size_t)SEQ * EMB + (size_t)SEQ * G4); // 2*1024 u64

    k_init<<<1, 256, 0, stream>>>(emo_ids, emo_emb, eave, htag);
    k_cvec<<<64, 256, 0, stream>>>(comb_W, comb_b, eave, cvec);
    // C = relu( gather(word_emb, sent_ids) @ W_x^T + cvec ),  W_x = comb_W[:, :1024]
    dim3 g1(EMB / 128, SEQ / 128);
    k_gemm<<<g1, 256, 0, stream>>>(nullptr, sent_ids, word_emb,
                                   comb_W, 2048, cvec, nullptr, C, EMB, 1);
    // G = C @ W_ih^T + b_ih + b_hh
    dim3 g2(G4 / 128, SEQ / 128);
    k_gemm<<<g2, 256, 0, stream>>>(C, nullptr, nullptr,
                                   W_ih, 1024, b_ih, b_hh, G, G4, 0);
    k_lstm<<<NB, 512, 0, stream>>>(W_hh, G, htag);
    k_out<<<1, 448, 0, stream>>>(out_W, out_b, htag, out);
}

// Round 5
// 5036.842 us; speedup vs baseline: 4.6905x; 1.1306x over previous
//
#include <hip/hip_runtime.h>
#include <hip/hip_bf16.h>
#include <stdint.h>
#include <math.h>

// Problem constants (fixed by the reference)
#define SEQ    2048
#define EMB    1024
#define HID    1024
#define G4     4096      // 4*HID
#define NEMO   16
#define NLAB   7

// LSTM persistent-kernel partition: 128 blocks x 256 threads.
// Block b owns 8 hidden units -> 32 gate rows (4 gates x 8 units).
// Thread t: wave wv = t>>6 handles rows {wv, wv+4, ..., wv+28} over h-columns
// [lane*16, lane*16+16). W fragment = 8x16 = 128 VGPRs.
//
// Exchange-structure ledger (rounds 1-4): R2 (16 polled slots/lane, no LDS)
// = 5.3x WORSE; R3 (padded slots + 8 single-lane stores) = 1.7x worse;
// R4 (64x512, 2 slots/lane, full-line 16-lane store) = 1.15x worse.
// Poll volume and store false-sharing measured NON-binding; step time is the
// agent-scope store -> coherence point -> poll-observe round trip (~2.1 us).
// This R1 structure is the measured optimum of the family.
#define NB 128

__device__ __forceinline__ float sigf(float x) { return 1.0f / (1.0f + expf(-x)); }

// ---------------- k_init: emoji average + htag reset ----------------
__global__ void k_init(const int* __restrict__ emoji_ids,
                       const float* __restrict__ emoji_emb,
                       float* __restrict__ eave,
                       unsigned long long* __restrict__ htag)
{
    int t = threadIdx.x;
    int ids[NEMO];
#pragma unroll
    for (int n = 0; n < NEMO; ++n) ids[n] = emoji_ids[n];
    for (int e = t; e < EMB; e += 256) {
        float s = 0.f;
#pragma unroll
        for (int n = 0; n < NEMO; ++n) s += emoji_emb[(size_t)ids[n] * EMB + e];
        eave[e] = s * (1.0f / 16.0f);
    }
    // htag[2][HID]: tag=0, value=0.0f  (h_{-1} = zeros, parity-1 buffer)
    for (int i = t; i < 2 * HID; i += 256) htag[i] = 0ull;
}

// ---------------- k_cvec: cvec = comb_W[:,1024:] @ eave + comb_b ----------------
__global__ void k_cvec(const float* __restrict__ combW,
                       const float* __restrict__ combB,
                       const float* __restrict__ eave,
                       float* __restrict__ cvec)
{
    // 64 blocks x 256 threads = 256 waves; 4 rows per wave
    int gw   = (blockIdx.x * 256 + threadIdx.x) >> 6;
    int lane = threadIdx.x & 63;
#pragma unroll
    for (int rr = 0; rr < 4; ++rr) {
        int r = gw * 4 + rr;
        const float* wrow = combW + (size_t)r * 2048 + 1024;
        float s = 0.f;
        for (int k = lane; k < EMB; k += 64) s = fmaf(wrow[k], eave[k], s);
#pragma unroll
        for (int off = 1; off < 64; off <<= 1) s += __shfl_xor(s, off);
        if (lane == 0) cvec[r] = s + combB[r];
    }
}

// ---------------- k_gemm: O[m][n] = sum_k Arow(m)[k]*B[n*bstride+k] + bias (+relu) ----
// BM=BN=128, BK=16, 256 threads, 8x8 microtile. K fixed at 1024, dims divide evenly.
__global__ __launch_bounds__(256) void k_gemm(
    const float* __restrict__ Asrc,
    const int*   __restrict__ ids,       // if non-null: A row m = emb[ids[m]]
    const float* __restrict__ emb,
    const float* __restrict__ B, int bstride,
    const float* __restrict__ bias1,
    const float* __restrict__ bias2,     // optional second bias
    float* __restrict__ O, int N, int relu)
{
    __shared__ float As[16][128];
    __shared__ float Bs[16][128];
    const int tid  = threadIdx.x;
    const int row0 = blockIdx.y * 128;
    const int col0 = blockIdx.x * 128;
    const int lr = tid >> 2;     // 0..63: staging row
    const int kq = tid & 3;      // 0..3 : k quad
    const float *ar0, *ar1;
    if (ids) {
        ar0 = emb + (size_t)ids[row0 + lr]      * 1024;
        ar1 = emb + (size_t)ids[row0 + lr + 64] * 1024;
    } else {
        ar0 = Asrc + (size_t)(row0 + lr)      * 1024;
        ar1 = Asrc + (size_t)(row0 + lr + 64) * 1024;
    }
    const float* br0 = B + (size_t)(col0 + lr)      * bstride;
    const float* br1 = B + (size_t)(col0 + lr + 64) * bstride;
    const int tx = tid & 15, ty = tid >> 4;

    float acc[8][8];
#pragma unroll
    for (int i = 0; i < 8; ++i)
#pragma unroll
        for (int j = 0; j < 8; ++j) acc[i][j] = 0.f;

    for (int k0 = 0; k0 < 1024; k0 += 16) {
        float4 a0 = *(const float4*)(ar0 + k0 + kq * 4);
        float4 a1 = *(const float4*)(ar1 + k0 + kq * 4);
        float4 b0 = *(const float4*)(br0 + k0 + kq * 4);
        float4 b1 = *(const float4*)(br1 + k0 + kq * 4);
        __syncthreads();
        {
            const float* pa0 = &a0.x; const float* pa1 = &a1.x;
            const float* pb0 = &b0.x; const float* pb1 = &b1.x;
#pragma unroll
            for (int e = 0; e < 4; ++e) {
                As[kq * 4 + e][lr]      = pa0[e];
                As[kq * 4 + e][lr + 64] = pa1[e];
                Bs[kq * 4 + e][lr]      = pb0[e];
                Bs[kq * 4 + e][lr + 64] = pb1[e];
            }
        }
        __syncthreads();
#pragma unroll
        for (int kk = 0; kk < 16; ++kk) {
            float af[8], bf[8];
            *(float4*)(af)     = *(const float4*)&As[kk][ty * 8];
            *(float4*)(af + 4) = *(const float4*)&As[kk][ty * 8 + 4];
            *(float4*)(bf)     = *(const float4*)&Bs[kk][tx * 8];
            *(float4*)(bf + 4) = *(const float4*)&Bs[kk][tx * 8 + 4];
#pragma unroll
            for (int i = 0; i < 8; ++i)
#pragma unroll
                for (int j = 0; j < 8; ++j)
                    acc[i][j] = fmaf(af[i], bf[j], acc[i][j]);
        }
    }
    // epilogue
    float bv[8];
    *(float4*)(bv)     = *(const float4*)&bias1[col0 + tx * 8];
    *(float4*)(bv + 4) = *(const float4*)&bias1[col0 + tx * 8 + 4];
    if (bias2) {
        float b2[8];
        *(float4*)(b2)     = *(const float4*)&bias2[col0 + tx * 8];
        *(float4*)(b2 + 4) = *(const float4*)&bias2[col0 + tx * 8 + 4];
#pragma unroll
        for (int j = 0; j < 8; ++j) bv[j] += b2[j];
    }
#pragma unroll
    for (int i = 0; i < 8; ++i) {
        int m = row0 + ty * 8 + i;
        float o[8];
#pragma unroll
        for (int j = 0; j < 8; ++j) {
            float v = acc[i][j] + bv[j];
            o[j] = relu ? fmaxf(v, 0.f) : v;
        }
        *(float4*)&O[(size_t)m * N + col0 + tx * 8]     = *(float4*)(o);
        *(float4*)&O[(size_t)m * N + col0 + tx * 8 + 4] = *(float4*)(o + 4);
    }
}

// ---------------- k_lstm: persistent sequential scan ----------------
// htag[2][HID] slots: (tag<<32)|float_bits, agent-scope atomics (coherent across XCDs).
// Step s: reads parity (s+1)&1 expecting tag s; writes parity s&1 with tag s+1.
__global__ __launch_bounds__(256, 1) void k_lstm(
    const float* __restrict__ Whh,     // [4096][1024]
    const float* __restrict__ Gin,     // [2048][4096] precomputed input-gate terms
    unsigned long long* __restrict__ htag)
{
    const int b    = blockIdx.x;    // 0..127, owns units [8b, 8b+8)
    const int t    = threadIdx.x;   // 0..255
    const int lane = t & 63;
    const int wv   = t >> 6;        // wave id 0..3

    // W_hh fragment: 8 rows (wv+4i), cols [lane*16, lane*16+16)
    float w[8][16];
#pragma unroll
    for (int i = 0; i < 8; ++i) {
        int r = wv + 4 * i;
        int grow = ((r >> 3) << 10) + (b << 3) + (r & 7);
        const float4* p = (const float4*)(Whh + (size_t)grow * HID + lane * 16);
#pragma unroll
        for (int q = 0; q < 4; ++q) {
            float4 a = p[q];
            w[i][4 * q + 0] = a.x; w[i][4 * q + 1] = a.y;
            w[i][4 * q + 2] = a.z; w[i][4 * q + 3] = a.w;
        }
    }

    __shared__ float4 hl4[256];        // h, float4-swizzled: hl4[j4*64+col] = h[col*16+j4*4 ..]
    __shared__ float  red[32 * 72];    // per-row partials, padded stride 72
    __shared__ float  gat[32];         // 32 gate pre-activations
    __shared__ float  cst[8];          // persistent cell state (this block's units)
    if (t < 8) cst[t] = 0.f;

    const int s_j4 = t & 3, s_col = t >> 2;     // staging slot for h values 4t..4t+3
    const int rr = t >> 3, kk = t & 7;          // reduction role
    const int growR = ((rr >> 3) << 10) + (b << 3) + (rr & 7);
    unsigned long long* myslots0 = htag + 4 * t;  // + parity*HID at use

    for (int s = 0; s < SEQ; ++s) {
        // prefetch this step's G_in rows (independent of h) — one per row
        float gval = 0.f;
        if (kk == 0) gval = Gin[(size_t)s * G4 + growR];

        // poll h_{s-1}: 4 tagged slots per thread
        unsigned long long* src = myslots0 + (size_t)(((unsigned)(s + 1)) & 1u) * HID;
        const unsigned expw = (unsigned)s;
        unsigned long long v0, v1, v2, v3;
        for (;;) {
            v0 = __hip_atomic_load(src + 0, __ATOMIC_RELAXED, __HIP_MEMORY_SCOPE_AGENT);
            v1 = __hip_atomic_load(src + 1, __ATOMIC_RELAXED, __HIP_MEMORY_SCOPE_AGENT);
            v2 = __hip_atomic_load(src + 2, __ATOMIC_RELAXED, __HIP_MEMORY_SCOPE_AGENT);
            v3 = __hip_atomic_load(src + 3, __ATOMIC_RELAXED, __HIP_MEMORY_SCOPE_AGENT);
            int ok = ((unsigned)(v0 >> 32) == expw) & ((unsigned)(v1 >> 32) == expw) &
                     ((unsigned)(v2 >> 32) == expw) & ((unsigned)(v3 >> 32) == expw);
            if (__all(ok)) break;
        }
        hl4[s_j4 * 64 + s_col] = make_float4(
            __uint_as_float((unsigned)v0), __uint_as_float((unsigned)v1),
            __uint_as_float((unsigned)v2), __uint_as_float((unsigned)v3));
        __syncthreads();   // S1: h staged

        float hf[16];
#pragma unroll
        for (int q = 0; q < 4; ++q) {
            float4 hv = hl4[q * 64 + lane];
            hf[4 * q + 0] = hv.x; hf[4 * q + 1] = hv.y;
            hf[4 * q + 2] = hv.z; hf[4 * q + 3] = hv.w;
        }
        float p[8];
#pragma unroll
        for (int i = 0; i < 8; ++i) p[i] = 0.f;
#pragma unroll
        for (int j = 0; j < 16; ++j)
#pragma unroll
            for (int i = 0; i < 8; ++i)
                p[i] = fmaf(w[i][j], hf[j], p[i]);
#pragma unroll
        for (int i = 0; i < 8; ++i) red[(wv + 4 * i) * 72 + lane] = p[i];
        __syncthreads();   // S2: partials written

        float rs = 0.f;
#pragma unroll
        for (int j = 0; j < 8; ++j) rs += red[rr * 72 + j * 8 + kk];
        rs += __shfl_xor(rs, 1);
        rs += __shfl_xor(rs, 2);
        rs += __shfl_xor(rs, 4);
        if (kk == 0) gat[rr] = rs + gval;
        __syncthreads();   // S3: gates assembled

        if (t < 8) {
            float gi = gat[t], gf = gat[8 + t], gg = gat[16 + t], go = gat[24 + t];
            float c = sigf(gf) * cst[t] + sigf(gi) * tanhf(gg);
            cst[t] = c;
            float h = sigf(go) * tanhf(c);
            unsigned long long pk =
                ((unsigned long long)(unsigned)(s + 1) << 32) |
                (unsigned long long)__float_as_uint(h);
            __hip_atomic_store(htag + (size_t)(((unsigned)s) & 1u) * HID + b * 8 + t,
                               pk, __ATOMIC_RELAXED, __HIP_MEMORY_SCOPE_AGENT);
        }
        // No trailing barrier needed: next step's S1/S2 protect all shared buffers.
    }
}

// ---------------- k_out: out = out_W @ h_final + out_b ----------------
__global__ void k_out(const float* __restrict__ outW,
                      const float* __restrict__ outb,
                      const unsigned long long* __restrict__ htag,
                      float* __restrict__ out)
{
    int wv = threadIdx.x >> 6, lane = threadIdx.x & 63;   // 7 waves
    if (wv < NLAB) {
        float s = 0.f;
        for (int k = lane; k < HID; k += 64) {
            float h = __uint_as_float((unsigned)(htag[HID + k] & 0xffffffffULL));
            s = fmaf(outW[wv * HID + k], h, s);
        }
#pragma unroll
        for (int off = 1; off < 64; off <<= 1) s += __shfl_xor(s, off);
        if (lane == 0) out[wv] = s + outb[wv];
    }
}

extern "C" void kernel_launch(void* const* d_in, const int* in_sizes, int n_in,
                              void* d_out, int out_size, void* d_ws, size_t ws_size,
                              hipStream_t stream)
{
    const int*   sent_ids = (const int*)  d_in[0];
    const int*   emo_ids  = (const int*)  d_in[1];
    const float* word_emb = (const float*)d_in[2];
    const float* emo_emb  = (const float*)d_in[3];
    // d_in[4] attn_W, d_in[5] attn_b: unused — softmax over a single logit == 1.0
    const float* comb_W   = (const float*)d_in[6];
    const float* comb_b   = (const float*)d_in[7];
    const float* W_ih     = (const float*)d_in[8];
    const float* W_hh     = (const float*)d_in[9];
    const float* b_ih     = (const float*)d_in[10];
    const float* b_hh     = (const float*)d_in[11];
    const float* out_W    = (const float*)d_in[12];
    const float* out_b    = (const float*)d_in[13];
    float* out = (float*)d_out;

    float* ws   = (float*)d_ws;
    float* eave = ws;                                   // 1024
    float* cvec = ws + 1024;                            // 1024 (pad to 4096)
    float* C    = ws + 4096;                            // 2048*1024
    float* G    = ws + 4096 + (size_t)SEQ * EMB;        // 2048*4096
    unsigned long long* htag =
        (unsigned long long*)(ws + 4096 + (size_t)SEQ * EMB + (size_t)SEQ * G4); // 2*1024 u64

    k_init<<<1, 256, 0, stream>>>(emo_ids, emo_emb, eave, htag);
    k_cvec<<<64, 256, 0, stream>>>(comb_W, comb_b, eave, cvec);
    // C = relu( gather(word_emb, sent_ids) @ W_x^T + cvec ),  W_x = comb_W[:, :1024]
    dim3 g1(EMB / 128, SEQ / 128);
    k_gemm<<<g1, 256, 0, stream>>>(nullptr, sent_ids, word_emb,
                                   comb_W, 2048, cvec, nullptr, C, EMB, 1);
    // G = C @ W_ih^T + b_ih + b_hh
    dim3 g2(G4 / 128, SEQ / 128);
    k_gemm<<<g2, 256, 0, stream>>>(C, nullptr, nullptr,
                                   W_ih, 1024, b_ih, b_hh, G, G4, 0);
    k_lstm<<<NB, 256, 0, stream>>>(W_hh, G, htag);
    k_out<<<1, 448, 0, stream>>>(out_W, out_b, htag, out);
}